// Round 1
// baseline (851.497 us; speedup 1.0000x reference)
//
#include <hip/hip_runtime.h>
#include <cstdint>
#include <cstddef>

// ---------------------------------------------------------------------------
// CausalSelfAttention, B=4 T=2048 C=2048 H=16 D=128, fp32 in/out.
// Pipeline: cvt(fp32->bf16) -> GEMM1 (qkv, scatter to Q/K/V BHTD) -> rope(Q,K)
//           -> flash attention (bf16 MFMA, online softmax) -> GEMM2 (proj, fp32 out)
// Workspace layout (bytes):
//   0         Wq_b   (6144x2048 bf16)  25165824
//   25165824  Wp_b   (2048x2048 bf16)   8388608
//   33554432  x_b    (8192x2048 bf16)  33554432
//   67108864  Qb     (B,H,T,D bf16)    33554432
//   100663296 Kb                        33554432
//   134217728 Vb                        33554432
//   167772160 Yb     (8192x2048 bf16)  33554432
//   total 201326592 (192 MiB)
// ---------------------------------------------------------------------------

typedef unsigned short u16;
typedef u16    u16x8 __attribute__((ext_vector_type(8)));
typedef __bf16 bf16x8 __attribute__((ext_vector_type(8)));
typedef float  f32x4 __attribute__((ext_vector_type(4)));

#define MFMA16(a, b, c) __builtin_amdgcn_mfma_f32_16x16x32_bf16( \
    __builtin_bit_cast(bf16x8, (a)), __builtin_bit_cast(bf16x8, (b)), (c), 0, 0, 0)

static __device__ __forceinline__ u16 f2b(float f) {
  unsigned u = __builtin_bit_cast(unsigned, f);
  unsigned r = (u + 0x7FFFu + ((u >> 16) & 1u)) >> 16;   // RNE
  return (u16)r;
}
static __device__ __forceinline__ float b2f(u16 v) {
  return __builtin_bit_cast(float, (unsigned)v << 16);
}

// async global->LDS, 16B per lane; lds dest = (wave-uniform base) + lane*16
static __device__ __forceinline__ void gld_lds16(const void* g, void* l) {
  __builtin_amdgcn_global_load_lds(
      (__attribute__((address_space(1))) unsigned int*)(void*)(g),
      (__attribute__((address_space(3))) unsigned int*)(l),
      16, 0, 0);
}

// ---------------------------------------------------------------------------
// fp32 -> bf16 conversion, 8 elements/thread
// ---------------------------------------------------------------------------
__global__ __launch_bounds__(256) void cvt_bf16(const float4* __restrict__ src,
                                                u16x8* __restrict__ dst, int n8) {
  int i = blockIdx.x * 256 + threadIdx.x;
  if (i >= n8) return;
  float4 a = src[i * 2], b = src[i * 2 + 1];
  u16x8 o;
  o[0] = f2b(a.x); o[1] = f2b(a.y); o[2] = f2b(a.z); o[3] = f2b(a.w);
  o[4] = f2b(b.x); o[5] = f2b(b.y); o[6] = f2b(b.z); o[7] = f2b(b.w);
  dst[i] = o;
}

// ---------------------------------------------------------------------------
// In-place rope on Q,K (B,H,T,D bf16). One wave per 128-elem row.
// out[j]    = q[2j]*cos - q[2j+1]*sin
// out[j+64] = q[2j]*sin + q[2j+1]*cos ,  theta_j = t * freqs[j]
// ---------------------------------------------------------------------------
__global__ __launch_bounds__(256) void rope_qk(u16* __restrict__ Qb, u16* __restrict__ Kb,
                                               const float* __restrict__ freqs) {
  int wv = threadIdx.x >> 6, lane = threadIdx.x & 63;
  long rid = (long)blockIdx.x * 4 + wv;       // 0 .. 2*B*H*T-1
  int isK = (int)(rid >> 17);                 // B*H*T = 131072 = 1<<17
  long r = rid & ((1L << 17) - 1);
  int t = (int)(r & 2047);
  u16* p = (isK ? Kb : Qb) + r * 128;
  unsigned w = *(const unsigned*)(p + 2 * lane);
  float q1 = b2f((u16)(w & 0xFFFF)), q2 = b2f((u16)(w >> 16));
  float th = (float)t * freqs[lane];
  float s = sinf(th), c = cosf(th);
  u16 olo = f2b(q1 * c - q2 * s);
  u16 ohi = f2b(q1 * s + q2 * c);
  p[lane] = olo;
  p[lane + 64] = ohi;
}

// ---------------------------------------------------------------------------
// bf16 B^T GEMM: out[m][n] = sum_k A[m][k] * Bw[n][k]
// 128x128 tile, BK=64, 4 waves (2x2), each wave 4x4 of 16x16x32 MFMAs.
// LDS XOR-swizzle (chunk ^= m&7) -> 2-way max bank aliasing on ds_read_b128.
// MODE 0: scatter-epilogue into Q/K/V (B,H,T,D) bf16. MODE 1: fp32 row-major out.
// ---------------------------------------------------------------------------
template <int MODE>
__global__ __launch_bounds__(256) void gemm_bt(
    const u16* __restrict__ A, const u16* __restrict__ Bw,
    int M, int N, int K,
    float* __restrict__ out,
    u16* __restrict__ Qp, u16* __restrict__ Kp, u16* __restrict__ Vp) {
  __shared__ alignas(16) u16 lA[128 * 64];
  __shared__ alignas(16) u16 lB[128 * 64];
  const int tid = threadIdx.x;
  const int lane = tid & 63, wv = tid >> 6;
  const int quad = lane >> 4, col = lane & 15;
  const int wm = wv & 1, wn = wv >> 1;
  const int m0 = blockIdx.y * 128, n0 = blockIdx.x * 128;

  f32x4 acc[4][4];
#pragma unroll
  for (int i = 0; i < 4; ++i)
#pragma unroll
    for (int j = 0; j < 4; ++j) acc[i][j] = (f32x4){0.f, 0.f, 0.f, 0.f};

  for (int k0 = 0; k0 < K; k0 += 64) {
    __syncthreads();
    // stage A,B tiles: chunk ci = (m, c); stored chunk c holds source chunk c^(m&7)
#pragma unroll
    for (int u = 0; u < 4; ++u) {
      int ci = ((wv * 4 + u) << 6) + lane;  // 0..1023
      int m = ci >> 3, c = ci & 7;
      int sc = c ^ (m & 7);
      const u16* ga = A + (size_t)(m0 + m) * K + k0 + (sc << 3);
      gld_lds16(ga, lA + ((size_t)(wv * 4 + u) << 9));
      const u16* gb = Bw + (size_t)(n0 + m) * K + k0 + (sc << 3);
      gld_lds16(gb, lB + ((size_t)(wv * 4 + u) << 9));
    }
    __syncthreads();
#pragma unroll
    for (int t = 0; t < 2; ++t) {
      u16x8 af[4], bf[4];
#pragma unroll
      for (int i = 0; i < 4; ++i) {
        int m = wm * 64 + i * 16 + col;
        int ca = ((t << 2) | quad) ^ (m & 7);
        af[i] = *(const u16x8*)&lA[(m * 8 + ca) * 8];
        int n = wn * 64 + i * 16 + col;
        int cb = ((t << 2) | quad) ^ (n & 7);
        bf[i] = *(const u16x8*)&lB[(n * 8 + cb) * 8];
      }
#pragma unroll
      for (int i = 0; i < 4; ++i)
#pragma unroll
        for (int j = 0; j < 4; ++j) acc[i][j] = MFMA16(af[i], bf[j], acc[i][j]);
    }
  }

  // epilogue: C/D layout row = quad*4+reg, col = lane&15
  if (MODE == 0) {
#pragma unroll
    for (int i = 0; i < 4; ++i) {
      int mg = m0 + wm * 64 + i * 16 + quad * 4;
#pragma unroll
      for (int j = 0; j < 4; ++j) {
        int ng = n0 + wn * 64 + j * 16 + col;
        int which = ng >> 11;          // 0=Q 1=K 2=V
        int cc = ng & 2047;
        int h = cc >> 7, d = cc & 127;
        u16* dstb = (which == 0) ? Qp : (which == 1) ? Kp : Vp;
#pragma unroll
        for (int r = 0; r < 4; ++r) {
          int m = mg + r;
          int b = m >> 11, t = m & 2047;
          size_t off = ((((size_t)(b * 16 + h)) << 11 | (size_t)t) << 7) | (size_t)d;
          dstb[off] = f2b(acc[i][j][r]);
        }
      }
    }
  } else {
#pragma unroll
    for (int i = 0; i < 4; ++i) {
      int mg = m0 + wm * 64 + i * 16 + quad * 4;
#pragma unroll
      for (int j = 0; j < 4; ++j) {
        int ng = n0 + wn * 64 + j * 16 + col;
#pragma unroll
        for (int r = 0; r < 4; ++r) out[(size_t)(mg + r) * N + ng] = acc[i][j][r];
      }
    }
  }
}

// ---------------------------------------------------------------------------
// Flash attention, causal. One block per (128 q rows, b*h). 4 waves x 32 rows.
// BC = 64 K/V rows per iteration. bf16 MFMA 16x16x32 for QK^T and PV.
// ---------------------------------------------------------------------------
__global__ __launch_bounds__(256) void fattn(
    const u16* __restrict__ Qb, const u16* __restrict__ Kb, const u16* __restrict__ Vb,
    u16* __restrict__ Yb) {
  __shared__ alignas(16) u16 lK[64 * 136];    // K tile, row stride 136 (pad 8)
  __shared__ alignas(16) u16 lVt[128 * 72];   // V^T tile, row stride 72 (pad 8)
  __shared__ alignas(16) u16 lP[4][32 * 72];  // per-wave P, A-operand layout

  const int tid = threadIdx.x;
  const int lane = tid & 63, wv = tid >> 6;
  const int quad = lane >> 4, col = lane & 15;

  const int qblk = (int)(gridDim.x - 1 - blockIdx.x);  // heavy blocks first
  const int bh = blockIdx.y;
  const int b = bh >> 4, h = bh & 15;
  const size_t base = (size_t)bh * 2048 * 128;
  const int qrow0 = qblk * 128 + wv * 32;
  const float scale = 0.08838834764831845f;  // 1/sqrt(128)

  // Q fragments (A-operand): 2 m-tiles x 4 k-tiles of 32
  u16x8 qf[2][4];
#pragma unroll
  for (int m = 0; m < 2; ++m)
#pragma unroll
    for (int t = 0; t < 4; ++t)
      qf[m][t] = *(const u16x8*)(Qb + base + (size_t)(qrow0 + m * 16 + col) * 128 + t * 32 + quad * 8);

  f32x4 mrow[2], lrow[2], o[2][8];
#pragma unroll
  for (int m = 0; m < 2; ++m) {
    mrow[m] = (f32x4){-1e30f, -1e30f, -1e30f, -1e30f};
    lrow[m] = (f32x4){0.f, 0.f, 0.f, 0.f};
#pragma unroll
    for (int dt = 0; dt < 8; ++dt) o[m][dt] = (f32x4){0.f, 0.f, 0.f, 0.f};
  }

  const int nkt = 2 * qblk + 2;
  for (int kt = 0; kt < nkt; ++kt) {
    __syncthreads();
    // stage K tile (coalesced 16B chunks)
#pragma unroll
    for (int u = 0; u < 4; ++u) {
      int id = u * 256 + tid;
      int row = id >> 4, ch = id & 15;
      u16x8 kv = *(const u16x8*)(Kb + base + (size_t)(kt * 64 + row) * 128 + ch * 8);
      *(u16x8*)&lK[row * 136 + ch * 8] = kv;
    }
    // stage V transposed: lane=kc, wave=dchunk -> conflict-free b16 writes
    {
      int kc = lane, dch = wv;
      const u16* vr = Vb + base + (size_t)(kt * 64 + kc) * 128 + dch * 32;
#pragma unroll
      for (int c2 = 0; c2 < 4; ++c2) {
        u16x8 vvv = *(const u16x8*)(vr + c2 * 8);
#pragma unroll
        for (int e = 0; e < 8; ++e) lVt[(dch * 32 + c2 * 8 + e) * 72 + kc] = vvv[e];
      }
    }
    __syncthreads();

    bool act = (kt * 64) <= (qrow0 + 31);
    if (act) {
#pragma unroll
      for (int m = 0; m < 2; ++m) {
        f32x4 sv[4];
#pragma unroll
        for (int nt = 0; nt < 4; ++nt) {
          f32x4 s = (f32x4){0.f, 0.f, 0.f, 0.f};
#pragma unroll
          for (int t = 0; t < 4; ++t) {
            u16x8 kf = *(const u16x8*)&lK[(nt * 16 + col) * 136 + t * 32 + quad * 8];
            s = MFMA16(qf[m][t], kf, s);
          }
          sv[nt] = s;
        }
        // scale + causal mask
#pragma unroll
        for (int nt = 0; nt < 4; ++nt) {
          int cg = kt * 64 + nt * 16 + col;
#pragma unroll
          for (int r = 0; r < 4; ++r) {
            int qg = qrow0 + m * 16 + quad * 4 + r;
            float x = sv[nt][r] * scale;
            sv[nt][r] = (cg <= qg) ? x : -1e30f;
          }
        }
        // row max across 4 nt and 16 lanes of the quad
        f32x4 mloc = sv[0];
#pragma unroll
        for (int nt = 1; nt < 4; ++nt)
#pragma unroll
          for (int r = 0; r < 4; ++r) mloc[r] = fmaxf(mloc[r], sv[nt][r]);
#pragma unroll
        for (int off = 1; off < 16; off <<= 1)
#pragma unroll
          for (int r = 0; r < 4; ++r) mloc[r] = fmaxf(mloc[r], __shfl_xor(mloc[r], off));
        f32x4 mnew, alpha, psum;
#pragma unroll
        for (int r = 0; r < 4; ++r) {
          mnew[r] = fmaxf(mrow[m][r], mloc[r]);
          alpha[r] = __expf(mrow[m][r] - mnew[r]);
          mrow[m][r] = mnew[r];
          psum[r] = 0.f;
        }
        // P = exp(S - mnew), write to LDS in A-operand layout
#pragma unroll
        for (int nt = 0; nt < 4; ++nt)
#pragma unroll
          for (int r = 0; r < 4; ++r) {
            float p = __expf(sv[nt][r] - mnew[r]);
            psum[r] += p;
            lP[wv][(m * 16 + quad * 4 + r) * 72 + nt * 16 + col] = f2b(p);
          }
#pragma unroll
        for (int off = 1; off < 16; off <<= 1)
#pragma unroll
          for (int r = 0; r < 4; ++r) psum[r] += __shfl_xor(psum[r], off);
#pragma unroll
        for (int r = 0; r < 4; ++r) lrow[m][r] = lrow[m][r] * alpha[r] + psum[r];
#pragma unroll
        for (int dt = 0; dt < 8; ++dt)
#pragma unroll
          for (int r = 0; r < 4; ++r) o[m][dt][r] *= alpha[r];
      }
    }
    __syncthreads();
    if (act) {
#pragma unroll
      for (int t = 0; t < 2; ++t) {
        u16x8 pf0 = *(const u16x8*)&lP[wv][(col)*72 + t * 32 + quad * 8];
        u16x8 pf1 = *(const u16x8*)&lP[wv][(16 + col) * 72 + t * 32 + quad * 8];
#pragma unroll
        for (int dt = 0; dt < 8; ++dt) {
          u16x8 vf = *(const u16x8*)&lVt[(dt * 16 + col) * 72 + t * 32 + quad * 8];
          o[0][dt] = MFMA16(pf0, vf, o[0][dt]);
          o[1][dt] = MFMA16(pf1, vf, o[1][dt]);
        }
      }
    }
  }

  // normalize + write Y as (B*T, C) bf16 row-major
#pragma unroll
  for (int m = 0; m < 2; ++m) {
    f32x4 inv;
#pragma unroll
    for (int r = 0; r < 4; ++r) inv[r] = 1.0f / lrow[m][r];
#pragma unroll
    for (int dt = 0; dt < 8; ++dt)
#pragma unroll
      for (int r = 0; r < 4; ++r) {
        float y = o[m][dt][r] * inv[r];
        int q = qrow0 + m * 16 + quad * 4 + r;
        size_t off = ((size_t)(b * 2048 + q)) * 2048 + h * 128 + dt * 16 + col;
        Yb[off] = f2b(y);
      }
  }
}

// ---------------------------------------------------------------------------
extern "C" void kernel_launch(void* const* d_in, const int* in_sizes, int n_in,
                              void* d_out, int out_size, void* d_ws, size_t ws_size,
                              hipStream_t stream) {
  (void)in_sizes; (void)n_in; (void)out_size; (void)ws_size;
  const float* x     = (const float*)d_in[0];
  const float* freqs = (const float*)d_in[1];
  const float* Wattn = (const float*)d_in[2];
  const float* Wproj = (const float*)d_in[3];
  float* out = (float*)d_out;
  char* ws = (char*)d_ws;

  u16* Wq_b = (u16*)(ws + 0);
  u16* Wp_b = (u16*)(ws + 25165824);
  u16* x_b  = (u16*)(ws + 33554432);
  u16* Qb   = (u16*)(ws + 67108864);
  u16* Kb   = (u16*)(ws + 100663296);
  u16* Vb   = (u16*)(ws + 134217728);
  u16* Yb   = (u16*)(ws + 167772160);

  cvt_bf16<<<6144, 256, 0, stream>>>((const float4*)Wattn, (u16x8*)Wq_b, 12582912 / 8);
  cvt_bf16<<<2048, 256, 0, stream>>>((const float4*)Wproj, (u16x8*)Wp_b, 4194304 / 8);
  cvt_bf16<<<8192, 256, 0, stream>>>((const float4*)x, (u16x8*)x_b, 16777216 / 8);

  // qkv = x @ W_attn^T, scattered into Q/K/V (B,H,T,D)
  gemm_bt<0><<<dim3(48, 64), 256, 0, stream>>>(x_b, Wq_b, 8192, 6144, 2048,
                                               nullptr, Qb, Kb, Vb);
  rope_qk<<<65536, 256, 0, stream>>>(Qb, Kb, freqs);
  fattn<<<dim3(16, 64), 256, 0, stream>>>(Qb, Kb, Vb, Yb);
  // out = y @ W_proj^T (fp32)
  gemm_bt<1><<<dim3(16, 64), 256, 0, stream>>>(Yb, Wp_b, 8192, 2048, 2048,
                                               out, nullptr, nullptr, nullptr);
}

// Round 2
// 735.212 us; speedup vs baseline: 1.1582x; 1.1582x over previous
//
#include <hip/hip_runtime.h>
#include <cstdint>
#include <cstddef>

// ---------------------------------------------------------------------------
// CausalSelfAttention, B=4 T=2048 C=2048 H=16 D=128, fp32 in/out.
// cvt(fp32->bf16) -> GEMM1 (qkv; Q,K as (B,H,T,D), V as (B,H,D,T) transposed)
// -> rope(Q,K) -> flash attention (paired q-tiles, async LDS staging)
// -> GEMM2 (proj, fp32 out)
// Workspace layout (bytes):
//   0         Wq_b   (6144x2048 bf16)  25165824
//   25165824  Wp_b   (2048x2048 bf16)   8388608
//   33554432  x_b    (8192x2048 bf16)  33554432
//   67108864  Qb     (B,H,T,D bf16)    33554432
//   100663296 Kb     (B,H,T,D bf16)    33554432
//   134217728 Vt     (B,H,D,T bf16)    33554432
//   167772160 Yb     (8192x2048 bf16)  33554432
// ---------------------------------------------------------------------------

typedef unsigned short u16;
typedef u16    u16x8 __attribute__((ext_vector_type(8)));
typedef __bf16 bf16x8 __attribute__((ext_vector_type(8)));
typedef float  f32x4 __attribute__((ext_vector_type(4)));

#define MFMA16(a, b, c) __builtin_amdgcn_mfma_f32_16x16x32_bf16( \
    __builtin_bit_cast(bf16x8, (a)), __builtin_bit_cast(bf16x8, (b)), (c), 0, 0, 0)

static __device__ __forceinline__ u16 f2b(float f) {
  unsigned u = __builtin_bit_cast(unsigned, f);
  unsigned r = (u + 0x7FFFu + ((u >> 16) & 1u)) >> 16;   // RNE
  return (u16)r;
}
static __device__ __forceinline__ float b2f(u16 v) {
  return __builtin_bit_cast(float, (unsigned)v << 16);
}

// async global->LDS, 16B per lane; lds dest = (wave-uniform base) + lane*16
static __device__ __forceinline__ void gld_lds16(const void* g, void* l) {
  __builtin_amdgcn_global_load_lds(
      (__attribute__((address_space(1))) unsigned int*)(void*)(g),
      (__attribute__((address_space(3))) unsigned int*)(l),
      16, 0, 0);
}

// ---------------------------------------------------------------------------
// fp32 -> bf16 conversion, 8 elements/thread
// ---------------------------------------------------------------------------
__global__ __launch_bounds__(256) void cvt_bf16(const float4* __restrict__ src,
                                                u16x8* __restrict__ dst, int n8) {
  int i = blockIdx.x * 256 + threadIdx.x;
  if (i >= n8) return;
  float4 a = src[i * 2], b = src[i * 2 + 1];
  u16x8 o;
  o[0] = f2b(a.x); o[1] = f2b(a.y); o[2] = f2b(a.z); o[3] = f2b(a.w);
  o[4] = f2b(b.x); o[5] = f2b(b.y); o[6] = f2b(b.z); o[7] = f2b(b.w);
  dst[i] = o;
}

// ---------------------------------------------------------------------------
// In-place rope on Q,K (B,H,T,D bf16). One wave per 128-elem row.
// ---------------------------------------------------------------------------
__global__ __launch_bounds__(256) void rope_qk(u16* __restrict__ Qb, u16* __restrict__ Kb,
                                               const float* __restrict__ freqs) {
  int wv = threadIdx.x >> 6, lane = threadIdx.x & 63;
  long rid = (long)blockIdx.x * 4 + wv;       // 0 .. 2*B*H*T-1
  int isK = (int)(rid >> 17);                 // B*H*T = 131072 = 1<<17
  long r = rid & ((1L << 17) - 1);
  int t = (int)(r & 2047);
  u16* p = (isK ? Kb : Qb) + r * 128;
  unsigned w = *(const unsigned*)(p + 2 * lane);
  float q1 = b2f((u16)(w & 0xFFFF)), q2 = b2f((u16)(w >> 16));
  float th = (float)t * freqs[lane];
  float s = sinf(th), c = cosf(th);
  u16 olo = f2b(q1 * c - q2 * s);
  u16 ohi = f2b(q1 * s + q2 * c);
  p[lane] = olo;
  p[lane + 64] = ohi;
}

// ---------------------------------------------------------------------------
// bf16 B^T GEMM: out[m][n] = sum_k A[m][k] * Bw[n][k]
// 128x128 tile, BK=64, 4 waves (2x2), each wave 4x4 of 16x16x32 MFMAs.
// MODE 0: scatter into Q (BHTD) / K (BHTD) / V^T (BHDT). MODE 1: fp32 out.
// ---------------------------------------------------------------------------
template <int MODE>
__global__ __launch_bounds__(256) void gemm_bt(
    const u16* __restrict__ A, const u16* __restrict__ Bw,
    int M, int N, int K,
    float* __restrict__ out,
    u16* __restrict__ Qp, u16* __restrict__ Kp, u16* __restrict__ Vp) {
  __shared__ alignas(16) u16 lA[128 * 64];
  __shared__ alignas(16) u16 lB[128 * 64];
  const int tid = threadIdx.x;
  const int lane = tid & 63, wv = tid >> 6;
  const int quad = lane >> 4, col = lane & 15;
  const int wm = wv & 1, wn = wv >> 1;
  const int m0 = blockIdx.y * 128, n0 = blockIdx.x * 128;

  f32x4 acc[4][4];
#pragma unroll
  for (int i = 0; i < 4; ++i)
#pragma unroll
    for (int j = 0; j < 4; ++j) acc[i][j] = (f32x4){0.f, 0.f, 0.f, 0.f};

  for (int k0 = 0; k0 < K; k0 += 64) {
    __syncthreads();
#pragma unroll
    for (int u = 0; u < 4; ++u) {
      int ci = ((wv * 4 + u) << 6) + lane;  // 0..1023
      int m = ci >> 3, c = ci & 7;
      int sc = c ^ (m & 7);
      const u16* ga = A + (size_t)(m0 + m) * K + k0 + (sc << 3);
      gld_lds16(ga, lA + ((size_t)(wv * 4 + u) << 9));
      const u16* gb = Bw + (size_t)(n0 + m) * K + k0 + (sc << 3);
      gld_lds16(gb, lB + ((size_t)(wv * 4 + u) << 9));
    }
    __syncthreads();
#pragma unroll
    for (int t = 0; t < 2; ++t) {
      u16x8 af[4], bf[4];
#pragma unroll
      for (int i = 0; i < 4; ++i) {
        int m = wm * 64 + i * 16 + col;
        int ca = ((t << 2) | quad) ^ (m & 7);
        af[i] = *(const u16x8*)&lA[(m * 8 + ca) * 8];
        int n = wn * 64 + i * 16 + col;
        int cb = ((t << 2) | quad) ^ (n & 7);
        bf[i] = *(const u16x8*)&lB[(n * 8 + cb) * 8];
      }
#pragma unroll
      for (int i = 0; i < 4; ++i)
#pragma unroll
        for (int j = 0; j < 4; ++j) acc[i][j] = MFMA16(af[i], bf[j], acc[i][j]);
    }
  }

  // epilogue: C/D layout row = quad*4+reg, col = lane&15
  if (MODE == 0) {
#pragma unroll
    for (int i = 0; i < 4; ++i) {
      int mg = m0 + wm * 64 + i * 16 + quad * 4;
#pragma unroll
      for (int j = 0; j < 4; ++j) {
        int ng = n0 + wn * 64 + j * 16 + col;
        int which = ng >> 11;          // 0=Q 1=K 2=V
        int cc = ng & 2047;
        int h = cc >> 7, d = cc & 127;
#pragma unroll
        for (int r = 0; r < 4; ++r) {
          int m = mg + r;
          int b = m >> 11, t = m & 2047;
          if (which == 2) {
            // V^T: (B,H,D,T)
            size_t off = (((size_t)(b * 16 + h) * 128 + d) << 11) | (size_t)t;
            Vp[off] = f2b(acc[i][j][r]);
          } else {
            size_t off = ((((size_t)(b * 16 + h)) << 11 | (size_t)t) << 7) | (size_t)d;
            (which == 0 ? Qp : Kp)[off] = f2b(acc[i][j][r]);
          }
        }
      }
    }
  } else {
#pragma unroll
    for (int i = 0; i < 4; ++i) {
      int mg = m0 + wm * 64 + i * 16 + quad * 4;
#pragma unroll
      for (int j = 0; j < 4; ++j) {
        int ng = n0 + wn * 64 + j * 16 + col;
#pragma unroll
        for (int r = 0; r < 4; ++r) out[(size_t)(mg + r) * N + ng] = acc[i][j][r];
      }
    }
  }
}

// ---------------------------------------------------------------------------
// Flash attention, causal, paired q-tiles for uniform work.
// Block (p, bh): phase0 = q-tile p (rows 64p..64p+63, p+1 kv iters),
//                phase1 = q-tile 31-p (rows 64(31-p).., 32-p kv iters).
// Every block: exactly 33 kv iterations. 4 waves x 16 q rows.
// LDS: lK 64x128 (xor-swizzled, async staged), lVt 128x64 from V^T global,
//      lP per-wave 16x64. Total 40960 B -> 4 blocks/CU.
// ---------------------------------------------------------------------------
__global__ __launch_bounds__(256, 4) void fattn(
    const u16* __restrict__ Qb, const u16* __restrict__ Kb, const u16* __restrict__ Vt,
    u16* __restrict__ Yb) {
  __shared__ alignas(16) u16 lK[64 * 128];
  __shared__ alignas(16) u16 lVt[128 * 64];
  __shared__ alignas(16) u16 lP[4][16 * 64];

  const int tid = threadIdx.x;
  const int lane = tid & 63, wv = tid >> 6;
  const int quad = lane >> 4, col = lane & 15;
  const int p = blockIdx.x, bh = blockIdx.y;
  const int b = bh >> 4, h = bh & 15;
  const size_t base = (size_t)bh << 18;  // * 2048 * 128
  const float kcomb = 0.08838834764831845f * 1.4426950408889634f;  // 1/sqrt(D)*log2(e)

#pragma unroll 1
  for (int phase = 0; phase < 2; ++phase) {
    const int tq = phase ? (31 - p) : p;
    const int q0 = tq << 6;
    const int qrw = q0 + wv * 16;   // this wave's 16 q rows

    u16x8 qf[4];
#pragma unroll
    for (int t = 0; t < 4; ++t)
      qf[t] = *(const u16x8*)(Qb + base + (size_t)(qrw + col) * 128 + t * 32 + quad * 8);

    f32x4 mrow = (f32x4){-1e30f, -1e30f, -1e30f, -1e30f};
    f32x4 lrow = (f32x4){0.f, 0.f, 0.f, 0.f};
    f32x4 o[8];
#pragma unroll
    for (int dt = 0; dt < 8; ++dt) o[dt] = (f32x4){0.f, 0.f, 0.f, 0.f};

#pragma unroll 1
    for (int kt = 0; kt <= tq; ++kt) {
      __syncthreads();
      // stage K tile (64 x 128, chunk16 xor row&15)
#pragma unroll
      for (int u = 0; u < 4; ++u) {
        int row = wv * 16 + u * 4 + (lane >> 4);
        int sc = (lane & 15) ^ (row & 15);
        gld_lds16(Kb + base + (size_t)(kt * 64 + row) * 128 + (sc << 3),
                  lK + (size_t)(wv * 16 + u * 4) * 128);
      }
      // stage V^T tile (128 x 64, chunk8 xor row&7)
#pragma unroll
      for (int u = 0; u < 4; ++u) {
        int row = wv * 32 + u * 8 + (lane >> 3);
        int sc = (lane & 7) ^ (row & 7);
        gld_lds16(Vt + base + (size_t)row * 2048 + kt * 64 + (sc << 3),
                  lVt + (size_t)(wv * 32 + u * 8) * 64);
      }
      __syncthreads();

      // QK^T: sv[nt] = Q(16 rows) x K(nt*16.. rows)
      f32x4 sv[4];
#pragma unroll
      for (int nt = 0; nt < 4; ++nt) {
        f32x4 s = (f32x4){0.f, 0.f, 0.f, 0.f};
#pragma unroll
        for (int t = 0; t < 4; ++t) {
          int krow = nt * 16 + col;
          u16x8 kf = *(const u16x8*)&lK[krow * 128 + ((((t << 2) | quad) ^ (krow & 15)) << 3)];
          s = MFMA16(qf[t], kf, s);
        }
        sv[nt] = s;
      }
      // to log2 domain; mask only the diagonal tile (kt == tq, block-uniform)
#pragma unroll
      for (int nt = 0; nt < 4; ++nt)
#pragma unroll
        for (int r = 0; r < 4; ++r) sv[nt][r] *= kcomb;
      if (kt == tq) {
#pragma unroll
        for (int nt = 0; nt < 4; ++nt) {
          int cg = nt * 16 + col;
#pragma unroll
          for (int r = 0; r < 4; ++r)
            if (cg > wv * 16 + quad * 4 + r) sv[nt][r] = -1e30f;
        }
      }
      // row max
      f32x4 mx = sv[0];
#pragma unroll
      for (int nt = 1; nt < 4; ++nt)
#pragma unroll
        for (int r = 0; r < 4; ++r) mx[r] = fmaxf(mx[r], sv[nt][r]);
#pragma unroll
      for (int off = 1; off < 16; off <<= 1)
#pragma unroll
        for (int r = 0; r < 4; ++r) mx[r] = fmaxf(mx[r], __shfl_xor(mx[r], off));
      f32x4 alpha;
#pragma unroll
      for (int r = 0; r < 4; ++r) {
        float mn = fmaxf(mrow[r], mx[r]);
        alpha[r] = exp2f(mrow[r] - mn);
        mrow[r] = mn;
      }
      // P = exp2(S - m), psum, write lP (row q'=quad*4+r, chunk8 xor row&7)
      f32x4 ps = (f32x4){0.f, 0.f, 0.f, 0.f};
#pragma unroll
      for (int nt = 0; nt < 4; ++nt)
#pragma unroll
        for (int r = 0; r < 4; ++r) {
          float pe = exp2f(sv[nt][r] - mrow[r]);
          ps[r] += pe;
          int row = quad * 4 + r;
          int ch = ((nt << 1) | (col >> 3)) ^ (row & 7);
          lP[wv][row * 64 + (ch << 3) + (col & 7)] = f2b(pe);
        }
#pragma unroll
      for (int off = 1; off < 16; off <<= 1)
#pragma unroll
        for (int r = 0; r < 4; ++r) ps[r] += __shfl_xor(ps[r], off);
#pragma unroll
      for (int r = 0; r < 4; ++r) lrow[r] = lrow[r] * alpha[r] + ps[r];
#pragma unroll
      for (int dt = 0; dt < 8; ++dt)
#pragma unroll
        for (int r = 0; r < 4; ++r) o[dt][r] *= alpha[r];
      // PV: o += P(16x64) x V^T
#pragma unroll
      for (int t = 0; t < 2; ++t) {
        u16x8 pf = *(const u16x8*)&lP[wv][col * 64 + ((((t << 2) | quad) ^ (col & 7)) << 3)];
#pragma unroll
        for (int dt = 0; dt < 8; ++dt) {
          int drow = dt * 16 + col;
          u16x8 vf = *(const u16x8*)&lVt[drow * 64 + ((((t << 2) | quad) ^ (drow & 7)) << 3)];
          o[dt] = MFMA16(pf, vf, o[dt]);
        }
      }
    }  // kt

    // epilogue: normalize + write Y (B*T, C) bf16
    f32x4 inv;
#pragma unroll
    for (int r = 0; r < 4; ++r) inv[r] = 1.0f / lrow[r];
#pragma unroll
    for (int dt = 0; dt < 8; ++dt)
#pragma unroll
      for (int r = 0; r < 4; ++r) {
        float y = o[dt][r] * inv[r];
        int q = qrw + quad * 4 + r;
        Yb[((size_t)(b * 2048 + q)) * 2048 + h * 128 + dt * 16 + col] = f2b(y);
      }
  }  // phase
}

// ---------------------------------------------------------------------------
extern "C" void kernel_launch(void* const* d_in, const int* in_sizes, int n_in,
                              void* d_out, int out_size, void* d_ws, size_t ws_size,
                              hipStream_t stream) {
  (void)in_sizes; (void)n_in; (void)out_size; (void)ws_size;
  const float* x     = (const float*)d_in[0];
  const float* freqs = (const float*)d_in[1];
  const float* Wattn = (const float*)d_in[2];
  const float* Wproj = (const float*)d_in[3];
  float* out = (float*)d_out;
  char* ws = (char*)d_ws;

  u16* Wq_b = (u16*)(ws + 0);
  u16* Wp_b = (u16*)(ws + 25165824);
  u16* x_b  = (u16*)(ws + 33554432);
  u16* Qb   = (u16*)(ws + 67108864);
  u16* Kb   = (u16*)(ws + 100663296);
  u16* Vt   = (u16*)(ws + 134217728);
  u16* Yb   = (u16*)(ws + 167772160);

  cvt_bf16<<<6144, 256, 0, stream>>>((const float4*)Wattn, (u16x8*)Wq_b, 12582912 / 8);
  cvt_bf16<<<2048, 256, 0, stream>>>((const float4*)Wproj, (u16x8*)Wp_b, 4194304 / 8);
  cvt_bf16<<<8192, 256, 0, stream>>>((const float4*)x, (u16x8*)x_b, 16777216 / 8);

  gemm_bt<0><<<dim3(48, 64), 256, 0, stream>>>(x_b, Wq_b, 8192, 6144, 2048,
                                               nullptr, Qb, Kb, Vt);
  rope_qk<<<65536, 256, 0, stream>>>(Qb, Kb, freqs);
  fattn<<<dim3(16, 64), 256, 0, stream>>>(Qb, Kb, Vt, Yb);
  gemm_bt<1><<<dim3(16, 64), 256, 0, stream>>>(Yb, Wp_b, 8192, 2048, 2048,
                                               out, nullptr, nullptr, nullptr);
}